// Round 2
// baseline (214.201 us; speedup 1.0000x reference)
//
#include <hip/hip_runtime.h>
#include <hip/hip_bf16.h>

typedef short short8 __attribute__((ext_vector_type(8)));
typedef short short4_t __attribute__((ext_vector_type(4)));
typedef float floatx4 __attribute__((ext_vector_type(4)));

#define DEVI __device__ __forceinline__

// Problem dims: B=4, T=4096, D=256, E=12 (4x k5, 4x k9, 4x k17), BT=16384
// Inputs fp32 (per reference), output fp32. MFMA operands converted to bf16.
// Block: 256 threads (4 waves), BM=32 tokens -> 512 blocks (2 blocks/CU).
//
// Workspace (bytes):
//   projWT bf16 [12][256(f)][256(d)]  @ 0          (1,572,864)
//   outWT  bf16 [256(f)][256(k)]      @ 1,572,864  (131,072)
//   rWT    bf16 [16(e)][256(d)]       @ 1,703,936  (8,192)  (e>=12 zeroed)

DEVI float bf2f(__hip_bfloat16 v) { return __bfloat162float(v); }
DEVI __hip_bfloat16 f2bf(float v) { return __float2bfloat16(v); }

// ---------------------------------------------------------------- prep ----
__global__ __launch_bounds__(256) void prep_kernel(
    const float* __restrict__ projW,   // [12][256(d)][256(f)] fp32
    const float* __restrict__ outW,    // [256(k)][256(f)] fp32
    const float* __restrict__ rW,      // [256(d)][12(e)] fp32
    __hip_bfloat16* __restrict__ projWT,
    __hip_bfloat16* __restrict__ outWT,
    __hip_bfloat16* __restrict__ rWT)
{
    int idx = blockIdx.x * 256 + threadIdx.x;
    if (idx < 786432) {
        int e = idx >> 16, d = (idx >> 8) & 255, f = idx & 255;
        projWT[(e << 16) + (f << 8) + d] = f2bf(projW[idx]);
    } else if (idx < 851968) {
        int j = idx - 786432;
        int k = j >> 8, f = j & 255;
        outWT[(f << 8) + k] = f2bf(outW[j]);
    } else if (idx < 856064) {
        int j = idx - 851968;
        int e = j >> 8, d = j & 255;
        rWT[(e << 8) + d] = (e < 12) ? f2bf(rW[d * 12 + e]) : f2bf(0.0f);
    }
}

// --------------------------------------------------------------- fused ----
// LDS map (bytes), total 64,000:
//   xs     bf16 [48][272]  @ 0       (26,112)   x tile incl. 16-row halo
//   As0    bf16 [32][264]  @ 26,112  (16,896)   A tile (w * conv) dbuf 0
//   As1    bf16 [32][264]  @ 43,008  (16,896)   dbuf 1
//   wts_s  f32  [32][12]   @ 59,904  ( 1,536)
//   psum   f32  [32][9]    @ 61,440  ( 1,152)
//   psq    f32  [32][9]    @ 62,592  ( 1,152)
//   muA    f32  [32]       @ 63,744
//   rsA    f32  [32]       @ 63,872
//   mixed  f32  [32][257]  @ 0       (aliases xs/As0; live after expert loop)
//   normed bf16 [32][264]  @ 43,008  (aliases As1; live after LN)

template<int K>
DEVI void conv_one(const float* __restrict__ cw,  // [K][256] fp32, this expert
                   const __hip_bfloat16* xs, const float* wts_s, int e,
                   __hip_bfloat16* dst, int d)
{
    float cwr[K];
#pragma unroll
    for (int j = 0; j < K; j++) cwr[j] = cw[j * 256 + d];
    float win[K - 1];
#pragma unroll
    for (int i = 0; i < K - 1; i++) win[i] = bf2f(xs[(16 - K + 1 + i) * 272 + d]);
#pragma unroll
    for (int t = 0; t < 32; t++) {
        float nv = bf2f(xs[(16 + t) * 272 + d]);
        float s = nv * cwr[K - 1];
#pragma unroll
        for (int i = 0; i < K - 1; i++) s += win[i] * cwr[i];
        float w = wts_s[t * 12 + e];
        dst[t * 264 + d] = f2bf(s * w);
#pragma unroll
        for (int i = 0; i + 1 < K - 1; i++) win[i] = win[i + 1];
        win[K - 2] = nv;
    }
}

DEVI void conv_dispatch(int e,
                        const float* ck5, const float* ck9, const float* ck17,
                        const __hip_bfloat16* xs, const float* wts_s,
                        __hip_bfloat16* dst, int d)
{
    if (e < 4)      conv_one<5>(ck5 + e * 5 * 256, xs, wts_s, e, dst, d);
    else if (e < 8) conv_one<9>(ck9 + (e - 4) * 9 * 256, xs, wts_s, e, dst, d);
    else            conv_one<17>(ck17 + (e - 8) * 17 * 256, xs, wts_s, e, dst, d);
}

// M=32 x N=256 x K=256 GEMM step; wave nq covers n in [nq*64, nq*64+64)
DEVI void gemm32(const __hip_bfloat16* __restrict__ A,   // LDS [32][264]
                 const __hip_bfloat16* __restrict__ Bg,  // global [256(n)][256(k)]
                 floatx4 (&acc)[2][4], int l16, int quad, int nq)
{
    const __hip_bfloat16* a0p = A + l16 * 264 + quad * 8;
    const __hip_bfloat16* a1p = a0p + 16 * 264;
    const __hip_bfloat16* bp  = Bg + (nq * 64 + l16) * 256 + quad * 8;
    short8 a0 = *(const short8*)(a0p);
    short8 a1 = *(const short8*)(a1p);
    short8 b0 = *(const short8*)(bp);
    short8 b1 = *(const short8*)(bp + 4096);
    short8 b2 = *(const short8*)(bp + 8192);
    short8 b3 = *(const short8*)(bp + 12288);
#pragma unroll
    for (int ks = 0; ks < 8; ks++) {
        short8 na0, na1, nb0, nb1, nb2, nb3;
        if (ks < 7) {
            const int kn = (ks + 1) * 32;
            na0 = *(const short8*)(a0p + kn);
            na1 = *(const short8*)(a1p + kn);
            nb0 = *(const short8*)(bp + kn);
            nb1 = *(const short8*)(bp + 4096 + kn);
            nb2 = *(const short8*)(bp + 8192 + kn);
            nb3 = *(const short8*)(bp + 12288 + kn);
        }
        acc[0][0] = __builtin_amdgcn_mfma_f32_16x16x32_bf16(a0, b0, acc[0][0], 0, 0, 0);
        acc[0][1] = __builtin_amdgcn_mfma_f32_16x16x32_bf16(a0, b1, acc[0][1], 0, 0, 0);
        acc[0][2] = __builtin_amdgcn_mfma_f32_16x16x32_bf16(a0, b2, acc[0][2], 0, 0, 0);
        acc[0][3] = __builtin_amdgcn_mfma_f32_16x16x32_bf16(a0, b3, acc[0][3], 0, 0, 0);
        acc[1][0] = __builtin_amdgcn_mfma_f32_16x16x32_bf16(a1, b0, acc[1][0], 0, 0, 0);
        acc[1][1] = __builtin_amdgcn_mfma_f32_16x16x32_bf16(a1, b1, acc[1][1], 0, 0, 0);
        acc[1][2] = __builtin_amdgcn_mfma_f32_16x16x32_bf16(a1, b2, acc[1][2], 0, 0, 0);
        acc[1][3] = __builtin_amdgcn_mfma_f32_16x16x32_bf16(a1, b3, acc[1][3], 0, 0, 0);
        if (ks < 7) { a0 = na0; a1 = na1; b0 = nb0; b1 = nb1; b2 = nb2; b3 = nb3; }
    }
}

__global__ __launch_bounds__(256, 2) void fused_kernel(
    const float* __restrict__ x,       // [4][4096][256] fp32
    const float* __restrict__ ck5,     // [4][5][256] fp32
    const float* __restrict__ ck9,     // [4][9][256] fp32
    const float* __restrict__ ck17,    // [4][17][256] fp32
    const float* __restrict__ projb,   // [12][256] fp32
    const float* __restrict__ rb,      // [12] fp32
    const float* __restrict__ gmm,     // [256] fp32
    const float* __restrict__ bta,     // [256] fp32
    const float* __restrict__ outb,    // [256] fp32
    const __hip_bfloat16* __restrict__ projWT,
    const __hip_bfloat16* __restrict__ outWT,
    const __hip_bfloat16* __restrict__ rWT,
    float* __restrict__ out)
{
    __shared__ __align__(16) char smem[64000];
    __hip_bfloat16* xs   = (__hip_bfloat16*)(smem);
    __hip_bfloat16* As0  = (__hip_bfloat16*)(smem + 26112);
    __hip_bfloat16* As1  = (__hip_bfloat16*)(smem + 43008);
    float* wts_s = (float*)(smem + 59904);
    float* psum  = (float*)(smem + 61440);
    float* psq   = (float*)(smem + 62592);
    float* muA   = (float*)(smem + 63744);
    float* rsA   = (float*)(smem + 63872);
    float* mixed = (float*)(smem);             // [32][257]
    __hip_bfloat16* normed = As1;              // [32][264]

    const int tid  = threadIdx.x;
    const int wave = tid >> 6;
    const int lane = tid & 63;
    const int quad = lane >> 4;
    const int l16  = lane & 15;
    const int nq   = wave;                     // n-quarter
    const int m0   = blockIdx.x * 32;          // global token base
    const int bb   = m0 >> 12;                 // batch
    const int t0   = m0 & 4095;

    // ---- stage x tile (rows = t0-16 .. t0+31), fp32 -> bf16 ----
    {
        const float* xb = x + (size_t)bb * 4096 * 256;
        for (int idx = tid; idx < 48 * 64; idx += 256) {
            int row = idx >> 6, c4 = (idx & 63) << 2;
            int gt = t0 - 16 + row;
            short4_t v = {0, 0, 0, 0};
            if (gt >= 0) {
                float4 f = *(const float4*)(xb + (size_t)gt * 256 + c4);
                __hip_bfloat16 b0 = f2bf(f.x), b1 = f2bf(f.y),
                               b2 = f2bf(f.z), b3 = f2bf(f.w);
                v[0] = *(short*)&b0; v[1] = *(short*)&b1;
                v[2] = *(short*)&b2; v[3] = *(short*)&b3;
            }
            *(short4_t*)(xs + row * 272 + c4) = v;
        }
    }
    __syncthreads();

    // ---- router: [32 tok x 256] @ rWT^T -> softmax -> wts_s (waves 0,1) ----
    if (wave < 2) {
        floatx4 ra = {0.f, 0.f, 0.f, 0.f};
        const __hip_bfloat16* ap = xs + (16 + wave * 16 + l16) * 272 + quad * 8;
        const __hip_bfloat16* bp = rWT + l16 * 256 + quad * 8;
#pragma unroll
        for (int kk = 0; kk < 256; kk += 32)
            ra = __builtin_amdgcn_mfma_f32_16x16x32_bf16(
                *(const short8*)(ap + kk), *(const short8*)(bp + kk), ra, 0, 0, 0);
        float rbv = (l16 < 12) ? rb[l16] : 0.f;
#pragma unroll
        for (int r = 0; r < 4; r++) {
            float v = (l16 < 12) ? (ra[r] + rbv) : -1e30f;
            float mx = v;
            mx = fmaxf(mx, __shfl_xor(mx, 1));
            mx = fmaxf(mx, __shfl_xor(mx, 2));
            mx = fmaxf(mx, __shfl_xor(mx, 4));
            mx = fmaxf(mx, __shfl_xor(mx, 8));
            float ex = (l16 < 12) ? __expf(v - mx) : 0.f;
            float sm = ex;
            sm += __shfl_xor(sm, 1);
            sm += __shfl_xor(sm, 2);
            sm += __shfl_xor(sm, 4);
            sm += __shfl_xor(sm, 8);
            if (l16 < 12) wts_s[(wave * 16 + quad * 4 + r) * 12 + l16] = ex / sm;
        }
    }
    __syncthreads();

    // ---- expert loop: A(e) = w * conv_e(x), acc += A(e) @ projW[e] ----
    floatx4 acc[2][4];
#pragma unroll
    for (int i = 0; i < 2; i++)
#pragma unroll
        for (int j = 0; j < 4; j++) acc[i][j] = {0.f, 0.f, 0.f, 0.f};

    conv_dispatch(0, ck5, ck9, ck17, xs, wts_s, As0, tid);
#pragma unroll 1
    for (int e = 0; e < 12; e++) {
        __syncthreads();
        __hip_bfloat16* AsW = (e & 1) ? As0 : As1;        // conv target (e+1)
        const __hip_bfloat16* AsR = (e & 1) ? As1 : As0;  // GEMM source (e)
        if (e < 11) conv_dispatch(e + 1, ck5, ck9, ck17, xs, wts_s, AsW, tid);
        gemm32(AsR, projWT + (e << 16), acc, l16, quad, nq);
    }
    __syncthreads();

    // ---- mixed = acc + sum_e w_e * proj_b[e] ----
#pragma unroll
    for (int mt = 0; mt < 2; mt++) {
#pragma unroll
        for (int r = 0; r < 4; r++) {
            const int row = mt * 16 + quad * 4 + r;
#pragma unroll
            for (int nt = 0; nt < 4; nt++) {
                const int col = nq * 64 + nt * 16 + l16;
                float bias = 0.f;
#pragma unroll
                for (int e2 = 0; e2 < 12; e2++)
                    bias += wts_s[row * 12 + e2] * projb[(e2 << 8) + col];
                mixed[row * 257 + col] = acc[mt][nt][r] + bias;
            }
        }
    }
    __syncthreads();

    // ---- LayerNorm ----
    {
        const int row = tid >> 3, part = tid & 7;
        float s = 0.f, s2 = 0.f;
#pragma unroll
        for (int jj = 0; jj < 32; jj++) {
            float v = mixed[row * 257 + part + jj * 8];
            s += v; s2 += v * v;
        }
        psum[row * 9 + part] = s;
        psq[row * 9 + part] = s2;
    }
    __syncthreads();
    if (tid < 32) {
        float s = 0.f, s2 = 0.f;
#pragma unroll
        for (int p = 0; p < 8; p++) { s += psum[tid * 9 + p]; s2 += psq[tid * 9 + p]; }
        float mu = s * 0.00390625f;
        float var = fmaxf(s2 * 0.00390625f - mu * mu, 0.f);
        muA[tid] = mu;
        rsA[tid] = rsqrtf(var + 1e-5f);
    }
    __syncthreads();
    for (int idx = tid; idx < 32 * 256; idx += 256) {
        int row = idx >> 8, col = idx & 255;
        float v = (mixed[row * 257 + col] - muA[row]) * rsA[row]
                  * gmm[col] + bta[col];
        normed[row * 264 + col] = f2bf(v);
    }
    __syncthreads();

    // ---- out = normed @ out_W + out_b (direct fp32 stores) ----
    floatx4 acc2[2][4];
#pragma unroll
    for (int i = 0; i < 2; i++)
#pragma unroll
        for (int j = 0; j < 4; j++) acc2[i][j] = {0.f, 0.f, 0.f, 0.f};
    gemm32(normed, outWT, acc2, l16, quad, nq);

    {
        float* ob = out + (size_t)m0 * 256;
#pragma unroll
        for (int mt = 0; mt < 2; mt++) {
#pragma unroll
            for (int r = 0; r < 4; r++) {
                const int row = mt * 16 + quad * 4 + r;
#pragma unroll
                for (int nt = 0; nt < 4; nt++) {
                    const int col = nq * 64 + nt * 16 + l16;
                    ob[row * 256 + col] = acc2[mt][nt][r] + outb[col];
                }
            }
        }
    }
}

// -------------------------------------------------------------- launch ----
extern "C" void kernel_launch(void* const* d_in, const int* in_sizes, int n_in,
                              void* d_out, int out_size, void* d_ws, size_t ws_size,
                              hipStream_t stream)
{
    (void)in_sizes; (void)n_in; (void)out_size; (void)ws_size;
    const float* x     = (const float*)d_in[0];
    const float* ck5   = (const float*)d_in[1];
    const float* ck9   = (const float*)d_in[2];
    const float* ck17  = (const float*)d_in[3];
    const float* projW = (const float*)d_in[4];
    const float* projb = (const float*)d_in[5];
    const float* rW    = (const float*)d_in[6];
    const float* rb    = (const float*)d_in[7];
    const float* outW  = (const float*)d_in[8];
    const float* outb  = (const float*)d_in[9];
    const float* gmm   = (const float*)d_in[10];
    const float* bta   = (const float*)d_in[11];

    __hip_bfloat16* projWT = (__hip_bfloat16*)d_ws;
    __hip_bfloat16* outWT  = (__hip_bfloat16*)((char*)d_ws + 1572864);
    __hip_bfloat16* rWT    = (__hip_bfloat16*)((char*)d_ws + 1703936);

    prep_kernel<<<dim3(3344), dim3(256), 0, stream>>>(projW, outW, rW,
                                                      projWT, outWT, rWT);
    fused_kernel<<<dim3(512), dim3(256), 0, stream>>>(
        x, ck5, ck9, ck17, projb, rb, gmm, bta, outb,
        projWT, outWT, rWT, (float*)d_out);
}